// Round 1
// baseline (4440.161 us; speedup 1.0000x reference)
//
#include <hip/hip_runtime.h>
#include <hip/hip_bf16.h>
#include <math.h>

#define H 32

// h[n][c] = sum_k x[n][k]*Wn[k][c] + bn[c]
__global__ void k_encode(const float* __restrict__ x, const float* __restrict__ Wn,
                         const float* __restrict__ bn, float* __restrict__ h,
                         int n, int fnode) {
  int gid = blockIdx.x * blockDim.x + threadIdx.x;
  int node = gid >> 5, c = gid & 31;
  if (node >= n) return;
  float acc = bn[c];
  for (int k = 0; k < fnode; ++k)
    acc = fmaf(x[node * fnode + k], Wn[k * H + c], acc);
  h[node * H + c] = acc;
}

// W2[l] = We @ le_w[l]  ([2,H]) ; b2[l] = be @ le_w[l] + le_b[l]
__global__ void k_fold(const float* __restrict__ We, const float* __restrict__ be,
                       const float* __restrict__ lew, const float* __restrict__ leb,
                       float* __restrict__ W2, float* __restrict__ b2, int L) {
  int gid = blockIdx.x * blockDim.x + threadIdx.x;
  if (gid >= L * H) return;
  int l = gid >> 5, c = gid & 31;
  const float* lw = lew + (size_t)l * H * H;
  float a0 = 0.f, a1 = 0.f, bb = leb[l * H + c];
  for (int j = 0; j < H; ++j) {
    float w = lw[j * H + c];
    a0 = fmaf(We[j], w, a0);
    a1 = fmaf(We[H + j], w, a1);
    bb = fmaf(be[j], w, bb);
  }
  W2[l * 2 * H + c] = a0;
  W2[l * 2 * H + H + c] = a1;
  b2[l * H + c] = bb;
}

__global__ void k_hist(const int* __restrict__ dst, unsigned* __restrict__ cnt, int e) {
  int i = blockIdx.x * blockDim.x + threadIdx.x;
  if (i < e) atomicAdd(&cnt[dst[i]], 1u);
}

// single-block chunked Hillis-Steele exclusive scan; writes row_ptr[0..n] and fill[0..n-1]
__global__ void k_scan(const unsigned* __restrict__ cnt, unsigned* __restrict__ row_ptr,
                       unsigned* __restrict__ fill, int n) {
  __shared__ unsigned s[1024];
  __shared__ unsigned carry_s;
  int tid = threadIdx.x;
  if (tid == 0) carry_s = 0u;
  __syncthreads();
  for (int base = 0; base < n; base += 1024) {
    int i = base + tid;
    unsigned v = (i < n) ? cnt[i] : 0u;
    s[tid] = v;
    __syncthreads();
    for (int off = 1; off < 1024; off <<= 1) {
      unsigned u = (tid >= off) ? s[tid - off] : 0u;
      __syncthreads();
      s[tid] += u;
      __syncthreads();
    }
    unsigned incl = s[tid];
    unsigned cb = carry_s;
    unsigned excl = cb + incl - v;
    if (i < n) { row_ptr[i] = excl; fill[i] = excl; }
    __syncthreads();
    if (tid == 0) carry_s = cb + s[1023];
    __syncthreads();
  }
  if (tid == 0) row_ptr[n] = carry_s;
}

// rec = {src_as_float, attr0, attr1, 0}
__global__ void k_scatter(const int* __restrict__ src, const int* __restrict__ dst,
                          const float* __restrict__ ea, unsigned* __restrict__ fill,
                          float4* __restrict__ recs, int e) {
  int i = blockIdx.x * blockDim.x + threadIdx.x;
  if (i >= e) return;
  int d = dst[i];
  unsigned pos = atomicAdd(&fill[d], 1u);
  float2 a = ((const float2*)ea)[i];
  recs[pos] = make_float4(__int_as_float(src[i]), a.x, a.y, 0.f);
}

// t[n][c] = sum_k h[n][k]*lnw[k][c] + lnb[c]
__global__ void k_t(const float* __restrict__ h, const float* __restrict__ lnw,
                    const float* __restrict__ lnb, float* __restrict__ t, int n) {
  __shared__ float sw[H * H];
  int tid = threadIdx.x;
  for (int i = tid; i < H * H; i += blockDim.x) sw[i] = lnw[i];
  __syncthreads();
  int gid = blockIdx.x * blockDim.x + tid;
  int node = gid >> 5, c = gid & 31;
  if (node >= n) return;
  float hv = h[node * H + c];
  float acc = lnb[c];
#pragma unroll
  for (int k = 0; k < H; ++k) {
    float hk = __shfl(hv, k, 32);
    acc = fmaf(hk, sw[k * H + c], acc);
  }
  t[node * H + c] = acc;
}

// per dst node (32 lanes): accumulate messages over CSR in-edges, then node update
__global__ void __launch_bounds__(256) k_layer(
    const float* __restrict__ h, const float* __restrict__ t,
    const unsigned* __restrict__ row_ptr, const float4* __restrict__ recs,
    const float* __restrict__ W2l, const float* __restrict__ b2l,
    const float* __restrict__ luw, const float* __restrict__ lub,
    float* __restrict__ hout, int n) {
  __shared__ float sw[2 * H * H];  // 8 KB: lu_w for this layer
  int tid = threadIdx.x;
  for (int i = tid; i < 2 * H * H; i += 256) sw[i] = luw[i];
  __syncthreads();
  int node = blockIdx.x * 8 + (tid >> 5);
  int c = tid & 31;
  if (node >= n) return;
  float w0 = W2l[c], w1 = W2l[H + c], bb = b2l[c];
  unsigned s0 = row_ptr[node], s1 = row_ptr[node + 1];
  float acc = 0.f;
  for (unsigned i = s0; i < s1; ++i) {
    float4 r = recs[i];
    int src = __float_as_int(r.x);
    float ee = fmaf(r.y, w0, fmaf(r.z, w1, bb));
    float xj = h[src * H + c];
    float tj = t[src * H + c];
    acc += xj + ee * (tj - xj);  // xj*(1-ee) + ee*tj
  }
  float hc = h[node * H + c];
  float o = lub[c];
#pragma unroll
  for (int k = 0; k < H; ++k) {
    float hk = __shfl(hc, k, 32);
    float ak = __shfl(acc, k, 32);
    o = fmaf(hk, sw[k * H + c], o);
    o = fmaf(ak, sw[(H + k) * H + c], o);
  }
  hout[node * H + c] = fmaxf(o, 0.f);
}

// classifier: sigmoid(relu(h@c1+b1)@c2 + b2)
__global__ void k_cls(const float* __restrict__ h, const float* __restrict__ c1w,
                      const float* __restrict__ c1b, const float* __restrict__ c2w,
                      const float* __restrict__ c2b, float* __restrict__ out, int n) {
  __shared__ float sw[H * H];
  int tid = threadIdx.x;
  for (int i = tid; i < H * H; i += blockDim.x) sw[i] = c1w[i];
  __syncthreads();
  int gid = blockIdx.x * blockDim.x + tid;
  int node = gid >> 5, c = gid & 31;
  if (node >= n) return;
  float hv = h[node * H + c];
  float z = c1b[c];
#pragma unroll
  for (int k = 0; k < H; ++k)
    z = fmaf(__shfl(hv, k, 32), sw[k * H + c], z);
  z = fmaxf(z, 0.f);
  float r = z * c2w[c];
#pragma unroll
  for (int m = 16; m >= 1; m >>= 1)
    r += __shfl_xor(r, m, 32);
  if (c == 0) out[node] = 1.f / (1.f + expf(-(r + c2b[0])));
}

extern "C" void kernel_launch(void* const* d_in, const int* in_sizes, int n_in,
                              void* d_out, int out_size, void* d_ws, size_t ws_size,
                              hipStream_t stream) {
  const float* x         = (const float*)d_in[0];
  const float* edge_attr = (const float*)d_in[1];
  const int*   edge_index= (const int*)d_in[2];
  const float* Wn        = (const float*)d_in[3];
  const float* bn        = (const float*)d_in[4];
  const float* We        = (const float*)d_in[5];
  const float* be        = (const float*)d_in[6];
  const float* ln_w      = (const float*)d_in[7];
  const float* ln_b      = (const float*)d_in[8];
  const float* le_w      = (const float*)d_in[9];
  const float* le_b      = (const float*)d_in[10];
  const float* lu_w      = (const float*)d_in[11];
  const float* lu_b      = (const float*)d_in[12];
  const float* c1w       = (const float*)d_in[13];
  const float* c1b       = (const float*)d_in[14];
  const float* c2w       = (const float*)d_in[15];
  const float* c2b       = (const float*)d_in[16];

  const int N_ = in_sizes[0] / 5;
  const int E_ = in_sizes[1] / 2;
  const int L_ = in_sizes[7] / (H * H);
  const int* src = edge_index;
  const int* dst = edge_index + E_;

  char* ws = (char*)d_ws;
  size_t off = 0;
  auto alloc = [&](size_t bytes) -> void* {
    void* p = ws + off;
    off = (off + bytes + 255) & ~(size_t)255;
    return p;
  };
  float*    hA      = (float*)alloc((size_t)N_ * H * 4);
  float*    hB      = (float*)alloc((size_t)N_ * H * 4);
  float*    t       = (float*)alloc((size_t)N_ * H * 4);
  unsigned* row_ptr = (unsigned*)alloc((size_t)(N_ + 1) * 4);
  unsigned* fill    = (unsigned*)alloc((size_t)N_ * 4);
  float4*   recs    = (float4*)alloc((size_t)E_ * 16);
  float*    W2      = (float*)alloc((size_t)L_ * 2 * H * 4);
  float*    b2      = (float*)alloc((size_t)L_ * H * 4);

  const int tb = 256;
  hipMemsetAsync(fill, 0, (size_t)N_ * 4, stream);
  k_encode<<<(N_ * 32 + tb - 1) / tb, tb, 0, stream>>>(x, Wn, bn, hA, N_, 5);
  k_fold<<<(L_ * H + 63) / 64, 64, 0, stream>>>(We, be, le_w, le_b, W2, b2, L_);
  k_hist<<<(E_ + tb - 1) / tb, tb, 0, stream>>>(dst, fill, E_);
  k_scan<<<1, 1024, 0, stream>>>(fill, row_ptr, fill, N_);
  k_scatter<<<(E_ + tb - 1) / tb, tb, 0, stream>>>(src, dst, edge_attr, fill, recs, E_);

  float* hc = hA;
  float* hn = hB;
  for (int l = 0; l < L_; ++l) {
    k_t<<<(N_ * 32 + tb - 1) / tb, tb, 0, stream>>>(
        hc, ln_w + (size_t)l * H * H, ln_b + (size_t)l * H, t, N_);
    k_layer<<<(N_ + 7) / 8, 256, 0, stream>>>(
        hc, t, row_ptr, recs, W2 + l * 2 * H, b2 + l * H,
        lu_w + (size_t)l * 2 * H * H, lu_b + (size_t)l * H, hn, N_);
    float* tmp = hc; hc = hn; hn = tmp;
  }
  k_cls<<<(N_ * 32 + tb - 1) / tb, tb, 0, stream>>>(hc, c1w, c1b, c2w, c2b, (float*)d_out, N_);
}

// Round 2
// 4085.137 us; speedup vs baseline: 1.0869x; 1.0869x over previous
//
#include <hip/hip_runtime.h>
#include <hip/hip_bf16.h>
#include <math.h>

#define H 32
#define SCB 1024

__device__ __forceinline__ unsigned f2bf(float f) {  // f32 -> bf16 bits, RNE
  unsigned u = __float_as_uint(f);
  return (u + 0x7fffu + ((u >> 16) & 1u)) >> 16;
}
__device__ __forceinline__ float bflo(unsigned p) { return __uint_as_float(p << 16); }
__device__ __forceinline__ float bfhi(unsigned p) { return __uint_as_float(p & 0xffff0000u); }

// h[n][c] = sum_k x[n][k]*Wn[k][c] + bn[c]
__global__ void k_encode(const float* __restrict__ x, const float* __restrict__ Wn,
                         const float* __restrict__ bn, float* __restrict__ h,
                         int n, int fnode) {
  int gid = blockIdx.x * blockDim.x + threadIdx.x;
  int node = gid >> 5, c = gid & 31;
  if (node >= n) return;
  float acc = bn[c];
  for (int k = 0; k < fnode; ++k)
    acc = fmaf(x[node * fnode + k], Wn[k * H + c], acc);
  h[node * H + c] = acc;
}

// W2[l] = We @ le_w[l]  ([2,H]) ; b2[l] = be @ le_w[l] + le_b[l]
__global__ void k_fold(const float* __restrict__ We, const float* __restrict__ be,
                       const float* __restrict__ lew, const float* __restrict__ leb,
                       float* __restrict__ W2, float* __restrict__ b2, int L) {
  int gid = blockIdx.x * blockDim.x + threadIdx.x;
  if (gid >= L * H) return;
  int l = gid >> 5, c = gid & 31;
  const float* lw = lew + (size_t)l * H * H;
  float a0 = 0.f, a1 = 0.f, bb = leb[l * H + c];
  for (int j = 0; j < H; ++j) {
    float w = lw[j * H + c];
    a0 = fmaf(We[j], w, a0);
    a1 = fmaf(We[H + j], w, a1);
    bb = fmaf(be[j], w, bb);
  }
  W2[l * 2 * H + c] = a0;
  W2[l * 2 * H + H + c] = a1;
  b2[l * H + c] = bb;
}

__global__ void k_hist(const int* __restrict__ dst, unsigned* __restrict__ cnt, int e) {
  int i = blockIdx.x * blockDim.x + threadIdx.x;
  if (i < e) atomicAdd(&cnt[dst[i]], 1u);
}

// two-level scan: per-block exclusive + block sums
__global__ void k_scan1(const unsigned* __restrict__ cnt, unsigned* __restrict__ out,
                        unsigned* __restrict__ bsum, int n) {
  __shared__ unsigned s[SCB];
  int i = blockIdx.x * SCB + threadIdx.x;
  unsigned v = (i < n) ? cnt[i] : 0u;
  s[threadIdx.x] = v;
  __syncthreads();
  for (int off = 1; off < SCB; off <<= 1) {
    unsigned u = (threadIdx.x >= off) ? s[threadIdx.x - off] : 0u;
    __syncthreads();
    s[threadIdx.x] += u;
    __syncthreads();
  }
  if (i < n) out[i] = s[threadIdx.x] - v;
  if (threadIdx.x == SCB - 1) bsum[blockIdx.x] = s[SCB - 1];
}

__global__ void k_scan2(const unsigned* __restrict__ bsum, unsigned* __restrict__ boff,
                        unsigned* __restrict__ total_out, int nb) {
  __shared__ unsigned s[SCB];
  unsigned v = ((int)threadIdx.x < nb) ? bsum[threadIdx.x] : 0u;
  s[threadIdx.x] = v;
  __syncthreads();
  for (int off = 1; off < SCB; off <<= 1) {
    unsigned u = (threadIdx.x >= off) ? s[threadIdx.x - off] : 0u;
    __syncthreads();
    s[threadIdx.x] += u;
    __syncthreads();
  }
  if ((int)threadIdx.x < nb) boff[threadIdx.x] = s[threadIdx.x] - v;
  if (threadIdx.x == SCB - 1) *total_out = s[SCB - 1];
}

__global__ void k_scan3(unsigned* __restrict__ row_ptr, const unsigned* __restrict__ boff,
                        unsigned* __restrict__ fill, int n) {
  int i = blockIdx.x * blockDim.x + threadIdx.x;
  if (i >= n) return;
  unsigned v = row_ptr[i] + boff[i >> 10];
  row_ptr[i] = v;
  fill[i] = v;
}

// rec = {src, bf16(attr0) | bf16(attr1)<<16}
__global__ void k_scatter(const int* __restrict__ src, const int* __restrict__ dst,
                          const float* __restrict__ ea, unsigned* __restrict__ fill,
                          uint2* __restrict__ recs, int e) {
  int i = blockIdx.x * blockDim.x + threadIdx.x;
  if (i >= e) return;
  int d = dst[i];
  unsigned pos = atomicAdd(&fill[d], 1u);
  float2 a = ((const float2*)ea)[i];
  recs[pos] = make_uint2((unsigned)src[i], f2bf(a.x) | (f2bf(a.y) << 16));
}

// t = h@lnw+lnb; pack pk[n][c] = {bf16(h), bf16(t-h)}
__global__ void k_tp(const float* __restrict__ h, const float* __restrict__ lnw,
                     const float* __restrict__ lnb, unsigned* __restrict__ pk, int n) {
  __shared__ float sw[H * H];
  int tid = threadIdx.x;
  for (int i = tid; i < H * H; i += blockDim.x) sw[i] = lnw[i];
  __syncthreads();
  int gid = blockIdx.x * blockDim.x + tid;
  int node = gid >> 5, c = gid & 31;
  if (node >= n) return;
  float hv = h[node * H + c];
  float acc = lnb[c];
#pragma unroll
  for (int k = 0; k < H; ++k) {
    float hk = __shfl(hv, k, 32);
    acc = fmaf(hk, sw[k * H + c], acc);
  }
  pk[node * H + c] = f2bf(hv) | (f2bf(acc - hv) << 16);
}

// per dst node (32 lanes): gather-accumulate messages, then node update
__global__ void __launch_bounds__(256) k_layer(
    const float* __restrict__ h, const unsigned* __restrict__ pk,
    const unsigned* __restrict__ row_ptr, const uint2* __restrict__ recs,
    const float* __restrict__ W2l, const float* __restrict__ b2l,
    const float* __restrict__ luw, const float* __restrict__ lub,
    float* __restrict__ hout, int n) {
  __shared__ float sw[2 * H * H];  // 8 KB: lu_w for this layer
  int tid = threadIdx.x;
  for (int i = tid; i < 2 * H * H; i += 256) sw[i] = luw[i];
  __syncthreads();
  int node = blockIdx.x * 8 + (tid >> 5);
  int c = tid & 31;
  if (node >= n) return;
  float w0 = W2l[c], w1 = W2l[H + c], bb = b2l[c];
  unsigned s0 = row_ptr[node], s1 = row_ptr[node + 1];
  float acc = 0.f;
  for (unsigned i = s0; i < s1; ++i) {
    uint2 r = recs[i];
    float ee = fmaf(bflo(r.y), w0, fmaf(bfhi(r.y), w1, bb));
    unsigned pv = pk[r.x * H + c];
    acc += bflo(pv);                 // + xj
    acc = fmaf(ee, bfhi(pv), acc);   // + ee*(tj-xj)
  }
  float hc = h[node * H + c];
  float o = lub[c];
#pragma unroll
  for (int k = 0; k < H; ++k) {
    float hk = __shfl(hc, k, 32);
    float ak = __shfl(acc, k, 32);
    o = fmaf(hk, sw[k * H + c], o);
    o = fmaf(ak, sw[(H + k) * H + c], o);
  }
  hout[node * H + c] = fmaxf(o, 0.f);
}

// classifier: sigmoid(relu(h@c1+b1)@c2 + b2)
__global__ void k_cls(const float* __restrict__ h, const float* __restrict__ c1w,
                      const float* __restrict__ c1b, const float* __restrict__ c2w,
                      const float* __restrict__ c2b, float* __restrict__ out, int n) {
  __shared__ float sw[H * H];
  int tid = threadIdx.x;
  for (int i = tid; i < H * H; i += blockDim.x) sw[i] = c1w[i];
  __syncthreads();
  int gid = blockIdx.x * blockDim.x + tid;
  int node = gid >> 5, c = gid & 31;
  if (node >= n) return;
  float hv = h[node * H + c];
  float z = c1b[c];
#pragma unroll
  for (int k = 0; k < H; ++k)
    z = fmaf(__shfl(hv, k, 32), sw[k * H + c], z);
  z = fmaxf(z, 0.f);
  float r = z * c2w[c];
#pragma unroll
  for (int m = 16; m >= 1; m >>= 1)
    r += __shfl_xor(r, m, 32);
  if (c == 0) out[node] = 1.f / (1.f + expf(-(r + c2b[0])));
}

extern "C" void kernel_launch(void* const* d_in, const int* in_sizes, int n_in,
                              void* d_out, int out_size, void* d_ws, size_t ws_size,
                              hipStream_t stream) {
  const float* x         = (const float*)d_in[0];
  const float* edge_attr = (const float*)d_in[1];
  const int*   edge_index= (const int*)d_in[2];
  const float* Wn        = (const float*)d_in[3];
  const float* bn        = (const float*)d_in[4];
  const float* We        = (const float*)d_in[5];
  const float* be        = (const float*)d_in[6];
  const float* ln_w      = (const float*)d_in[7];
  const float* ln_b      = (const float*)d_in[8];
  const float* le_w      = (const float*)d_in[9];
  const float* le_b      = (const float*)d_in[10];
  const float* lu_w      = (const float*)d_in[11];
  const float* lu_b      = (const float*)d_in[12];
  const float* c1w       = (const float*)d_in[13];
  const float* c1b       = (const float*)d_in[14];
  const float* c2w       = (const float*)d_in[15];
  const float* c2b       = (const float*)d_in[16];

  const int N_ = in_sizes[0] / 5;
  const int E_ = in_sizes[1] / 2;
  const int L_ = in_sizes[7] / (H * H);
  const int* src = edge_index;
  const int* dst = edge_index + E_;

  char* ws = (char*)d_ws;
  size_t off = 0;
  auto alloc = [&](size_t bytes) -> void* {
    void* p = ws + off;
    off = (off + bytes + 255) & ~(size_t)255;
    return p;
  };
  float*    hA      = (float*)alloc((size_t)N_ * H * 4);
  float*    hB      = (float*)alloc((size_t)N_ * H * 4);
  unsigned* pk      = (unsigned*)alloc((size_t)N_ * H * 4);
  unsigned* row_ptr = (unsigned*)alloc((size_t)(N_ + 1) * 4);
  unsigned* fill    = (unsigned*)alloc((size_t)N_ * 4);
  uint2*    recs    = (uint2*)alloc((size_t)E_ * 8);
  float*    W2      = (float*)alloc((size_t)L_ * 2 * H * 4);
  float*    b2      = (float*)alloc((size_t)L_ * H * 4);
  unsigned* bsum    = (unsigned*)alloc((size_t)SCB * 4);
  unsigned* boff    = (unsigned*)alloc((size_t)SCB * 4);

  const int tb = 256;
  const int nb = (N_ + SCB - 1) / SCB;
  hipMemsetAsync(fill, 0, (size_t)N_ * 4, stream);
  k_encode<<<(N_ * 32 + tb - 1) / tb, tb, 0, stream>>>(x, Wn, bn, hA, N_, 5);
  k_fold<<<(L_ * H + 63) / 64, 64, 0, stream>>>(We, be, le_w, le_b, W2, b2, L_);
  k_hist<<<(E_ + tb - 1) / tb, tb, 0, stream>>>(dst, fill, E_);
  k_scan1<<<nb, SCB, 0, stream>>>(fill, row_ptr, bsum, N_);
  k_scan2<<<1, SCB, 0, stream>>>(bsum, boff, row_ptr + N_, nb);
  k_scan3<<<(N_ + tb - 1) / tb, tb, 0, stream>>>(row_ptr, boff, fill, N_);
  k_scatter<<<(E_ + tb - 1) / tb, tb, 0, stream>>>(src, dst, edge_attr, fill, recs, E_);

  float* hc = hA;
  float* hn = hB;
  for (int l = 0; l < L_; ++l) {
    k_tp<<<(N_ * 32 + tb - 1) / tb, tb, 0, stream>>>(
        hc, ln_w + (size_t)l * H * H, ln_b + (size_t)l * H, pk, N_);
    k_layer<<<(N_ + 7) / 8, 256, 0, stream>>>(
        hc, pk, row_ptr, recs, W2 + l * 2 * H, b2 + l * H,
        lu_w + (size_t)l * 2 * H * H, lu_b + (size_t)l * H, hn, N_);
    float* tmp = hc; hc = hn; hn = tmp;
  }
  k_cls<<<(N_ * 32 + tb - 1) / tb, tb, 0, stream>>>(hc, c1w, c1b, c2w, c2b, (float*)d_out, N_);
}

// Round 3
// 2641.314 us; speedup vs baseline: 1.6810x; 1.5466x over previous
//
#include <hip/hip_runtime.h>
#include <hip/hip_bf16.h>
#include <math.h>

#define H 32
#define SCB 1024

__device__ __forceinline__ unsigned f2bf(float f) {  // f32 -> bf16 bits, RNE
  unsigned u = __float_as_uint(f);
  return (u + 0x7fffu + ((u >> 16) & 1u)) >> 16;
}
__device__ __forceinline__ float bflo(unsigned p) { return __uint_as_float(p << 16); }
__device__ __forceinline__ float bfhi(unsigned p) { return __uint_as_float(p & 0xffff0000u); }

// h = x@Wn+bn ; pk = {bf16(h), bf16(h@lnw0+lnb0 - h)}
__global__ void k_encode(const float* __restrict__ x, const float* __restrict__ Wn,
                         const float* __restrict__ bn, const float* __restrict__ lnw0,
                         const float* __restrict__ lnb0, float* __restrict__ h,
                         unsigned* __restrict__ pk, int n, int fnode) {
  __shared__ float sw[H * H];
  int tid = threadIdx.x;
  for (int i = tid; i < H * H; i += blockDim.x) sw[i] = lnw0[i];
  __syncthreads();
  int gid = blockIdx.x * blockDim.x + tid;
  int node = gid >> 5, c = gid & 31;
  if (node >= n) return;
  float acc = bn[c];
  for (int k = 0; k < fnode; ++k)
    acc = fmaf(x[node * fnode + k], Wn[k * H + c], acc);
  h[node * H + c] = acc;
  float t = lnb0[c];
#pragma unroll
  for (int k = 0; k < H; ++k)
    t = fmaf(__shfl(acc, k, 32), sw[k * H + c], t);
  pk[node * H + c] = f2bf(acc) | (f2bf(t - acc) << 16);
}

// W2[l] = We @ le_w[l]  ([2,H]) ; b2[l] = be @ le_w[l] + le_b[l]
__global__ void k_fold(const float* __restrict__ We, const float* __restrict__ be,
                       const float* __restrict__ lew, const float* __restrict__ leb,
                       float* __restrict__ W2, float* __restrict__ b2, int L) {
  int gid = blockIdx.x * blockDim.x + threadIdx.x;
  if (gid >= L * H) return;
  int l = gid >> 5, c = gid & 31;
  const float* lw = lew + (size_t)l * H * H;
  float a0 = 0.f, a1 = 0.f, bb = leb[l * H + c];
  for (int j = 0; j < H; ++j) {
    float w = lw[j * H + c];
    a0 = fmaf(We[j], w, a0);
    a1 = fmaf(We[H + j], w, a1);
    bb = fmaf(be[j], w, bb);
  }
  W2[l * 2 * H + c] = a0;
  W2[l * 2 * H + H + c] = a1;
  b2[l * H + c] = bb;
}

__global__ void k_hist(const int* __restrict__ dst, unsigned* __restrict__ cnt, int e) {
  int i = blockIdx.x * blockDim.x + threadIdx.x;
  if (i < e) atomicAdd(&cnt[dst[i]], 1u);
}

// two-level scan: per-block exclusive + block sums
__global__ void k_scan1(const unsigned* __restrict__ cnt, unsigned* __restrict__ out,
                        unsigned* __restrict__ bsum, int n) {
  __shared__ unsigned s[SCB];
  int i = blockIdx.x * SCB + threadIdx.x;
  unsigned v = (i < n) ? cnt[i] : 0u;
  s[threadIdx.x] = v;
  __syncthreads();
  for (int off = 1; off < SCB; off <<= 1) {
    unsigned u = (threadIdx.x >= off) ? s[threadIdx.x - off] : 0u;
    __syncthreads();
    s[threadIdx.x] += u;
    __syncthreads();
  }
  if (i < n) out[i] = s[threadIdx.x] - v;
  if (threadIdx.x == SCB - 1) bsum[blockIdx.x] = s[SCB - 1];
}

__global__ void k_scan2(const unsigned* __restrict__ bsum, unsigned* __restrict__ boff,
                        unsigned* __restrict__ total_out, int nb) {
  __shared__ unsigned s[SCB];
  unsigned v = ((int)threadIdx.x < nb) ? bsum[threadIdx.x] : 0u;
  s[threadIdx.x] = v;
  __syncthreads();
  for (int off = 1; off < SCB; off <<= 1) {
    unsigned u = (threadIdx.x >= off) ? s[threadIdx.x - off] : 0u;
    __syncthreads();
    s[threadIdx.x] += u;
    __syncthreads();
  }
  if ((int)threadIdx.x < nb) boff[threadIdx.x] = s[threadIdx.x] - v;
  if (threadIdx.x == SCB - 1) *total_out = s[SCB - 1];
}

__global__ void k_scan3(unsigned* __restrict__ row_ptr, const unsigned* __restrict__ boff,
                        unsigned* __restrict__ fill, int n) {
  int i = blockIdx.x * blockDim.x + threadIdx.x;
  if (i >= n) return;
  unsigned v = row_ptr[i] + boff[i >> 10];
  row_ptr[i] = v;
  fill[i] = v;
}

// rec = {src, bf16(attr0) | bf16(attr1)<<16}
__global__ void k_scatter(const int* __restrict__ src, const int* __restrict__ dst,
                          const float* __restrict__ ea, unsigned* __restrict__ fill,
                          uint2* __restrict__ recs, int e) {
  int i = blockIdx.x * blockDim.x + threadIdx.x;
  if (i >= e) return;
  int d = dst[i];
  unsigned pos = atomicAdd(&fill[d], 1u);
  float2 a = ((const float2*)ea)[i];
  recs[pos] = make_uint2((unsigned)src[i], f2bf(a.x) | (f2bf(a.y) << 16));
}

// per dst node (32 lanes): gather-accumulate messages (8-deep MLP), node update,
// then produce next layer's pk in the epilogue.
__global__ void __launch_bounds__(256) k_layer(
    const float* __restrict__ h, const unsigned* __restrict__ pk,
    const unsigned* __restrict__ row_ptr, const uint2* __restrict__ recs,
    const float* __restrict__ W2l, const float* __restrict__ b2l,
    const float* __restrict__ luw, const float* __restrict__ lub,
    const float* __restrict__ lnw_next, const float* __restrict__ lnb_next,
    float* __restrict__ hout, unsigned* __restrict__ pk_out, int n) {
  __shared__ float sw[2 * H * H];   // lu_w for this layer (8 KB)
  __shared__ float swn[H * H];      // ln_w for next layer (4 KB)
  int tid = threadIdx.x;
  for (int i = tid; i < 2 * H * H; i += 256) sw[i] = luw[i];
  if (lnw_next)
    for (int i = tid; i < H * H; i += 256) swn[i] = lnw_next[i];
  __syncthreads();
  int node = blockIdx.x * 8 + (tid >> 5);
  int c = tid & 31;
  if (node >= n) return;
  float w0 = W2l[c], w1 = W2l[H + c], bb = b2l[c];
  unsigned s0 = row_ptr[node], s1 = row_ptr[node + 1];
  float acc = 0.f;
  unsigned i = s0;
  for (; i + 8 <= s1; i += 8) {
    uint2 r0 = recs[i],     r1 = recs[i + 1], r2 = recs[i + 2], r3 = recs[i + 3];
    uint2 r4 = recs[i + 4], r5 = recs[i + 5], r6 = recs[i + 6], r7 = recs[i + 7];
    unsigned p0 = pk[r0.x * H + c], p1 = pk[r1.x * H + c];
    unsigned p2 = pk[r2.x * H + c], p3 = pk[r3.x * H + c];
    unsigned p4 = pk[r4.x * H + c], p5 = pk[r5.x * H + c];
    unsigned p6 = pk[r6.x * H + c], p7 = pk[r7.x * H + c];
    float e0 = fmaf(bflo(r0.y), w0, fmaf(bfhi(r0.y), w1, bb));
    float e1 = fmaf(bflo(r1.y), w0, fmaf(bfhi(r1.y), w1, bb));
    float e2 = fmaf(bflo(r2.y), w0, fmaf(bfhi(r2.y), w1, bb));
    float e3 = fmaf(bflo(r3.y), w0, fmaf(bfhi(r3.y), w1, bb));
    float e4 = fmaf(bflo(r4.y), w0, fmaf(bfhi(r4.y), w1, bb));
    float e5 = fmaf(bflo(r5.y), w0, fmaf(bfhi(r5.y), w1, bb));
    float e6 = fmaf(bflo(r6.y), w0, fmaf(bfhi(r6.y), w1, bb));
    float e7 = fmaf(bflo(r7.y), w0, fmaf(bfhi(r7.y), w1, bb));
    acc += bflo(p0); acc = fmaf(e0, bfhi(p0), acc);
    acc += bflo(p1); acc = fmaf(e1, bfhi(p1), acc);
    acc += bflo(p2); acc = fmaf(e2, bfhi(p2), acc);
    acc += bflo(p3); acc = fmaf(e3, bfhi(p3), acc);
    acc += bflo(p4); acc = fmaf(e4, bfhi(p4), acc);
    acc += bflo(p5); acc = fmaf(e5, bfhi(p5), acc);
    acc += bflo(p6); acc = fmaf(e6, bfhi(p6), acc);
    acc += bflo(p7); acc = fmaf(e7, bfhi(p7), acc);
  }
  for (; i < s1; ++i) {
    uint2 r = recs[i];
    float ee = fmaf(bflo(r.y), w0, fmaf(bfhi(r.y), w1, bb));
    unsigned pv = pk[r.x * H + c];
    acc += bflo(pv);
    acc = fmaf(ee, bfhi(pv), acc);
  }
  float hc = h[node * H + c];
  float o = lub[c];
#pragma unroll
  for (int k = 0; k < H; ++k) {
    float hk = __shfl(hc, k, 32);
    float ak = __shfl(acc, k, 32);
    o = fmaf(hk, sw[k * H + c], o);
    o = fmaf(ak, sw[(H + k) * H + c], o);
  }
  o = fmaxf(o, 0.f);
  hout[node * H + c] = o;
  if (pk_out) {
    float t = lnb_next[c];
#pragma unroll
    for (int k = 0; k < H; ++k)
      t = fmaf(__shfl(o, k, 32), swn[k * H + c], t);
    pk_out[node * H + c] = f2bf(o) | (f2bf(t - o) << 16);
  }
}

// classifier: sigmoid(relu(h@c1+b1)@c2 + b2)
__global__ void k_cls(const float* __restrict__ h, const float* __restrict__ c1w,
                      const float* __restrict__ c1b, const float* __restrict__ c2w,
                      const float* __restrict__ c2b, float* __restrict__ out, int n) {
  __shared__ float sw[H * H];
  int tid = threadIdx.x;
  for (int i = tid; i < H * H; i += blockDim.x) sw[i] = c1w[i];
  __syncthreads();
  int gid = blockIdx.x * blockDim.x + tid;
  int node = gid >> 5, c = gid & 31;
  if (node >= n) return;
  float hv = h[node * H + c];
  float z = c1b[c];
#pragma unroll
  for (int k = 0; k < H; ++k)
    z = fmaf(__shfl(hv, k, 32), sw[k * H + c], z);
  z = fmaxf(z, 0.f);
  float r = z * c2w[c];
#pragma unroll
  for (int m = 16; m >= 1; m >>= 1)
    r += __shfl_xor(r, m, 32);
  if (c == 0) out[node] = 1.f / (1.f + expf(-(r + c2b[0])));
}

extern "C" void kernel_launch(void* const* d_in, const int* in_sizes, int n_in,
                              void* d_out, int out_size, void* d_ws, size_t ws_size,
                              hipStream_t stream) {
  const float* x         = (const float*)d_in[0];
  const float* edge_attr = (const float*)d_in[1];
  const int*   edge_index= (const int*)d_in[2];
  const float* Wn        = (const float*)d_in[3];
  const float* bn        = (const float*)d_in[4];
  const float* We        = (const float*)d_in[5];
  const float* be        = (const float*)d_in[6];
  const float* ln_w      = (const float*)d_in[7];
  const float* ln_b      = (const float*)d_in[8];
  const float* le_w      = (const float*)d_in[9];
  const float* le_b      = (const float*)d_in[10];
  const float* lu_w      = (const float*)d_in[11];
  const float* lu_b      = (const float*)d_in[12];
  const float* c1w       = (const float*)d_in[13];
  const float* c1b       = (const float*)d_in[14];
  const float* c2w       = (const float*)d_in[15];
  const float* c2b       = (const float*)d_in[16];

  const int N_ = in_sizes[0] / 5;
  const int E_ = in_sizes[1] / 2;
  const int L_ = in_sizes[7] / (H * H);
  const int* src = edge_index;
  const int* dst = edge_index + E_;

  char* ws = (char*)d_ws;
  size_t off = 0;
  auto alloc = [&](size_t bytes) -> void* {
    void* p = ws + off;
    off = (off + bytes + 255) & ~(size_t)255;
    return p;
  };
  float*    hA      = (float*)alloc((size_t)N_ * H * 4);
  float*    hB      = (float*)alloc((size_t)N_ * H * 4);
  unsigned* pkA     = (unsigned*)alloc((size_t)N_ * H * 4);
  unsigned* pkB     = (unsigned*)alloc((size_t)N_ * H * 4);
  unsigned* row_ptr = (unsigned*)alloc((size_t)(N_ + 1) * 4);
  unsigned* fill    = (unsigned*)alloc((size_t)N_ * 4);
  uint2*    recs    = (uint2*)alloc((size_t)E_ * 8);
  float*    W2      = (float*)alloc((size_t)L_ * 2 * H * 4);
  float*    b2      = (float*)alloc((size_t)L_ * H * 4);
  unsigned* bsum    = (unsigned*)alloc((size_t)SCB * 4);
  unsigned* boff    = (unsigned*)alloc((size_t)SCB * 4);

  const int tb = 256;
  const int nb = (N_ + SCB - 1) / SCB;
  hipMemsetAsync(fill, 0, (size_t)N_ * 4, stream);
  k_encode<<<(N_ * 32 + tb - 1) / tb, tb, 0, stream>>>(x, Wn, bn, ln_w, ln_b, hA, pkA, N_, 5);
  k_fold<<<(L_ * H + 63) / 64, 64, 0, stream>>>(We, be, le_w, le_b, W2, b2, L_);
  k_hist<<<(E_ + tb - 1) / tb, tb, 0, stream>>>(dst, fill, E_);
  k_scan1<<<nb, SCB, 0, stream>>>(fill, row_ptr, bsum, N_);
  k_scan2<<<1, SCB, 0, stream>>>(bsum, boff, row_ptr + N_, nb);
  k_scan3<<<(N_ + tb - 1) / tb, tb, 0, stream>>>(row_ptr, boff, fill, N_);
  k_scatter<<<(E_ + tb - 1) / tb, tb, 0, stream>>>(src, dst, edge_attr, fill, recs, E_);

  float* hc = hA;  float* hn = hB;
  unsigned* pc = pkA; unsigned* pn = pkB;
  for (int l = 0; l < L_; ++l) {
    bool last = (l == L_ - 1);
    k_layer<<<(N_ + 7) / 8, 256, 0, stream>>>(
        hc, pc, row_ptr, recs, W2 + l * 2 * H, b2 + l * H,
        lu_w + (size_t)l * 2 * H * H, lu_b + (size_t)l * H,
        last ? nullptr : ln_w + (size_t)(l + 1) * H * H,
        last ? nullptr : ln_b + (size_t)(l + 1) * H,
        hn, last ? nullptr : pn, N_);
    float* tf = hc; hc = hn; hn = tf;
    unsigned* tp = pc; pc = pn; pn = tp;
  }
  k_cls<<<(N_ * 32 + tb - 1) / tb, tb, 0, stream>>>(hc, c1w, c1b, c2w, c2b, (float*)d_out, N_);
}